// Round 6
// baseline (206.287 us; speedup 1.0000x reference)
//
#include <hip/hip_runtime.h>
#include <stdint.h>
#include <math.h>

// ---------------------------------------------------------------------------
// JAX threefry2x32 (exact port of jax/_src/prng.py), usable on host + device.
// ---------------------------------------------------------------------------
__host__ __device__ static inline void tf2x32(uint32_t k0, uint32_t k1,
                                              uint32_t& x0, uint32_t& x1) {
  uint32_t ks2 = k0 ^ k1 ^ 0x1BD11BDAu;
  x0 += k0; x1 += k1;
#define TFR(r) { x0 += x1; x1 = (x1 << (r)) | (x1 >> (32 - (r))); x1 ^= x0; }
  TFR(13) TFR(15) TFR(26) TFR(6)
  x0 += k1;  x1 += ks2 + 1u;
  TFR(17) TFR(29) TFR(16) TFR(24)
  x0 += ks2; x1 += k0 + 2u;
  TFR(13) TFR(15) TFR(26) TFR(6)
  x0 += k0;  x1 += k1 + 3u;
  TFR(17) TFR(29) TFR(16) TFR(24)
  x0 += k1;  x1 += ks2 + 4u;
  TFR(13) TFR(15) TFR(26) TFR(6)
  x0 += ks2; x1 += k0 + 5u;
#undef TFR
}

struct Keys { uint32_t k[12]; };   // 6 subkeys (hi, lo) pairs

// ---------------------------------------------------------------------------
// constexpr tables: thresholds T[k] = 2^(k * l2p) and inverse prime powers.
// tmax = floor(log2(x)/l2p) = #{k in 1..63 : T[k] <= x}  (x >= 1).
// ---------------------------------------------------------------------------
struct DTab { double v[64]; };

constexpr double CEXP2(double w) {           // w >= 0
  long i = (long)w;                          // floor (w >= 0)
  double f = w - (double)i;
  double y = f * 0.69314718055994530941723212145818;  // ln2
  double term = 1.0, sum = 1.0;
  for (int k = 1; k <= 18; ++k) { term = term * y / (double)k; sum += term; }
  double p = 1.0;
  for (long k = 0; k < i; ++k) p *= 2.0;     // exact
  return sum * p;
}
constexpr DTab make_thresh(double l2p) {
  DTab t{};
  t.v[0] = 1e300;                            // lane 0 never counts
  for (int k = 1; k < 64; ++k) t.v[k] = CEXP2((double)k * l2p);
  return t;
}
constexpr DTab make_invpw(int p) {
  DTab t{};
  double pw = 1.0;
  for (int k = 0; k < 64; ++k) { t.v[k] = 1.0 / pw; pw *= (double)p; }
  return t;
}
// float32-rounded np.log2(prime) divisors (JAX x64-disabled demotion)
__constant__ DTab THR3 = make_thresh((double)1.5849625007211562f);  // log2(3)
__constant__ DTab THR5 = make_thresh((double)2.321928094887362f);   // log2(5)
__constant__ DTab THR7 = make_thresh((double)2.807354922057604f);   // log2(7)
__constant__ DTab IPW2 = make_invpw(2);
__constant__ DTab IPW3 = make_invpw(3);
__constant__ DTab IPW5 = make_invpw(5);

// ---------------------------------------------------------------------------
// DPP wave64 primitives (pure VALU, no DS pipe).
// ---------------------------------------------------------------------------
#define NEGINF_I 0xff800000            // bit pattern of -inf (max identity)

template <int CTRL, int RMASK>
__device__ __forceinline__ float dpp_max_step(float v) {
  int o = __builtin_amdgcn_update_dpp((int)NEGINF_I, __float_as_int(v),
                                      CTRL, RMASK, 0xf, false);
  return fmaxf(v, __int_as_float(o));
}
template <int CTRL, int RMASK>
__device__ __forceinline__ float dpp_add_step(float v) {
  int o = __builtin_amdgcn_update_dpp(0, __float_as_int(v),
                                      CTRL, RMASK, 0xf, false);
  return v + __int_as_float(o);
}
__device__ __forceinline__ float wave_max_bcast(float v) {   // full reduce
  v = dpp_max_step<0x111, 0xf>(v);
  v = dpp_max_step<0x112, 0xf>(v);
  v = dpp_max_step<0x114, 0xf>(v);
  v = dpp_max_step<0x118, 0xf>(v);
  v = dpp_max_step<0x142, 0xf>(v);
  v = dpp_max_step<0x143, 0xf>(v);
  return __int_as_float(__builtin_amdgcn_readlane(__float_as_int(v), 63));
}
__device__ __forceinline__ float wave_sum_bcast(float v) {   // full reduce
  v = dpp_add_step<0x111, 0xf>(v);
  v = dpp_add_step<0x112, 0xf>(v);
  v = dpp_add_step<0x114, 0xf>(v);
  v = dpp_add_step<0x118, 0xf>(v);
  v = dpp_add_step<0x142, 0xf>(v);
  v = dpp_add_step<0x143, 0xf>(v);
  return __int_as_float(__builtin_amdgcn_readlane(__float_as_int(v), 63));
}
__device__ __forceinline__ float wave_prefix_max(float v) {  // inclusive scan
  v = dpp_max_step<0x111, 0xf>(v);
  v = dpp_max_step<0x112, 0xf>(v);
  v = dpp_max_step<0x114, 0xf>(v);
  v = dpp_max_step<0x118, 0xf>(v);
  v = dpp_max_step<0x142, 0xa>(v);   // lane15 -> row1, lane47 -> row3
  v = dpp_max_step<0x143, 0xc>(v);   // lane31 -> rows 2,3
  return v;
}
__device__ __forceinline__ float wave_prefix_sum(float v) {  // inclusive scan
  v = dpp_add_step<0x111, 0xf>(v);
  v = dpp_add_step<0x112, 0xf>(v);
  v = dpp_add_step<0x114, 0xf>(v);
  v = dpp_add_step<0x118, 0xf>(v);
  v = dpp_add_step<0x142, 0xa>(v);
  v = dpp_add_step<0x143, 0xc>(v);
  return v;
}

__device__ __forceinline__ float readlane_f(float v, int lane) {
  return __int_as_float(__builtin_amdgcn_readlane(__float_as_int(v), lane));
}
__device__ __forceinline__ double readlane_d(double v, int lane) {
  union { double d; int i[2]; } u, r;
  u.d = v;
  r.i[0] = __builtin_amdgcn_readlane(u.i[0], lane);
  r.i[1] = __builtin_amdgcn_readlane(u.i[1], lane);
  return r.d;
}

// gumbel from threefry block (0, flat_idx), bits = x0 ^ x1 (partitionable)
__device__ static inline float gumbel_f(uint32_t k0, uint32_t k1,
                                        uint32_t flat_idx) {
  uint32_t x0 = 0u, x1 = flat_idx;
  tf2x32(k0, k1, x0, x1);
  uint32_t bits = x0 ^ x1;
  uint32_t fb = (bits >> 9) | 0x3f800000u;
  float f = __uint_as_float(fb) - 1.0f;                 // [0, 1-2^-23]
  const float tinyf = 1.1754943508222875e-38f;          // f32 tiny
  float u = fmaxf(tinyf, f + tinyf);                    // jax.random.uniform
  return -__logf(-__logf(u));                           // v_log_f32 x2
}

// All 21 outputs of a row are wave-uniform after the readlane/ballot steps.
struct RowRes {
  int   oa, spa, t2a, p1a, p2a, p3a;
  float lp0, lp1, lp2, lp3, lp4, lp5;
  float lm0, lm1, lm2, lm3, lm4, lm5;
};

// ---------------------------------------------------------------------------
// Process one batch row on the full wave. bs must be wave-uniform (SGPR).
// ---------------------------------------------------------------------------
__device__ static inline RowRes process_row(
    int bs, int t, int li, int O, int T, int P, int L, const Keys& keys,
    double thr3, double thr5, double thr7,
    double ipw2, double ipw3, double ipw5,
    const float* __restrict__ order_mask,
    const int*   __restrict__ tile_remain_budgets,
    const float* __restrict__ tile_masks,
    const float* __restrict__ remain_buffer_size,
    const int*   __restrict__ tile2_max,
    const float* __restrict__ max_temporal_tile2,
    const int*   __restrict__ sp_tile2_max,
    const int*   __restrict__ sp_tile2_min,
    const float* __restrict__ order_logit,
    const float* __restrict__ tile_logits,
    const float* __restrict__ sp_tile2_logit) {
  const float NEGINF = -__builtin_inff();

  // ---- action-independent precompute (full ILP) ----
  float g0 = gumbel_f(keys.k[0],  keys.k[1],  (uint32_t)(bs * O + t));
  uint32_t fT = (uint32_t)(bs * T + t);
  float g1 = gumbel_f(keys.k[2],  keys.k[3],  fT);   // sp
  float g2 = gumbel_f(keys.k[4],  keys.k[5],  fT);   // tile2
  float g3 = gumbel_f(keys.k[6],  keys.k[7],  fT);   // p=1
  float g4 = gumbel_f(keys.k[8],  keys.k[9],  fT);   // p=2
  float g5 = gumbel_f(keys.k[10], keys.k[11], fT);   // p=3

  float om  = (t < O) ? order_mask[(size_t)bs * O + t] : 1.0f;
  float osc = (t < O) ? (order_logit[(size_t)bs * O + t] + om) : NEGINF;

  const float* tm_row = tile_masks + ((size_t)bs * L + li) * P * T;
  const float* tl_row = tile_logits + (size_t)bs * P * T;
  float base0 = tm_row[t];
  float base1 = tm_row[T + t];
  float base2 = tm_row[2 * T + t];
  float base3 = tm_row[3 * T + t];

  int spmx = sp_tile2_max[bs], spmn = sp_tile2_min[bs];
  float spmask = (t > spmx || t < spmn) ? NEGINF : base0;
  float spsc   = sp_tile2_logit[(size_t)bs * T + t] + spmask;

  float sc2f = tl_row[t]         + base0;   // tile2 (p=0)
  float sc3f = tl_row[T + t]     + base1;   // p=1
  float sc4f = tl_row[2 * T + t] + base2;   // p=2
  float sc5f = tl_row[3 * T + t] + base3;   // p=3
  float es2f = __expf(sc2f), es3f = __expf(sc3f);
  float es4f = __expf(sc4f), es5f = __expf(sc5f);
  float z2f = sc2f + g2, z3f = sc3f + g3, z4f = sc4f + g4, z5f = sc5f + g5;

  // prefix structures (off-chain)
  float ps2 = wave_prefix_sum(es2f);
  float pm3 = wave_prefix_max(z3f), ps3 = wave_prefix_sum(es3f);
  float pm4 = wave_prefix_max(z4f), ps4 = wave_prefix_sum(es4f);
  float pm5 = wave_prefix_max(z5f), ps5 = wave_prefix_sum(es5f);

  const int* budg = tile_remain_budgets + ((size_t)bs * L + li) * P;
  int bu1 = budg[1], bu2 = budg[2], bu3 = budg[3];
  int t2maxcap = tile2_max[bs];
  int mt = (int)max_temporal_tile2[bs];     // trunc toward zero, >= 0
  float rbs = remain_buffer_size[bs];

  RowRes r;

  // ---- order sample (O=7: 8-lane mini-reduce, no deps) ----
  {
    float z0 = osc + g0;
    float es0 = __expf(osc);
    float mv = z0, sv = es0;
    mv = dpp_max_step<0x111, 0xf>(mv);
    mv = dpp_max_step<0x112, 0xf>(mv);
    mv = dpp_max_step<0x114, 0xf>(mv);      // lane 7 = max(lanes 0..7)
    sv = dpp_add_step<0x111, 0xf>(sv);
    sv = dpp_add_step<0x112, 0xf>(sv);
    sv = dpp_add_step<0x114, 0xf>(sv);      // lane 7 = sum(lanes 0..7)
    float zmax = readlane_f(mv, 7);
    unsigned long long ball = __ballot(z0 == zmax);
    r.oa = __builtin_amdgcn_readfirstlane(__ffsll(ball) - 1);
    float essum = readlane_f(sv, 7);
    r.lp0 = readlane_f(osc, r.oa) - __logf(essum);
    unsigned long long mb = __ballot((t < O) && (om == 0.0f));
    r.lm0 = (__popcll(mb) > 1) ? 1.0f : 0.0f;
  }

  // ---- sp sample (independent, two-sided mask) ----
  {
    float z1 = spsc + g1;
    float es1 = __expf(spsc);
    float zmax = wave_max_bcast(z1);
    unsigned long long ball = __ballot(z1 == zmax);
    r.spa = __builtin_amdgcn_readfirstlane(__ffsll(ball) - 1);
    float essum = wave_sum_bcast(es1);
    r.lp5 = readlane_f(spsc, r.spa) - __logf(essum);
    unsigned long long mb = __ballot(spmask == 0.0f);
    r.lm5 = (__popcll(mb) > 1) ? 1.0f : 0.0f;
  }

  // ---- tile2 sample (depends on sp action) ----
  {
    int t2min = r.spa;
    int t2mx = min(t2maxcap, t2min + mt);
    bool pv2 = (t <= t2mx) && (t >= t2min);
    float zm2 = pv2 ? z2f : NEGINF;
    float zmax = wave_max_bcast(zm2);              // only on-chain reduce
    unsigned long long ball = __ballot(zm2 == zmax);
    r.t2a = __builtin_amdgcn_readfirstlane(__ffsll(ball) - 1);
    float hi = readlane_f(ps2, t2mx);
    float lo = readlane_f(ps2, max(t2min - 1, 0));
    float essum = hi - ((t2min > 0) ? lo : 0.0f);  // prefix range-sum
    r.lp1 = readlane_f(sc2f, r.t2a) - __logf(essum);
    unsigned long long mb = __ballot(pv2 && (base0 == 0.0f));
    r.lm1 = (__popcll(mb) > 1) ? 1.0f : 0.0f;
  }

  // ---- p = 1..3 chain (prefix readlanes only) ----
  int prev = r.t2a;
#define P_STAGE(ACT, LP, LM, IPW, THR, BU, PM, PS, ZF, SCF, BASE)            \
  {                                                                          \
    rbs = (float)((double)rbs * readlane_d(IPW, prev));                      \
    double x = (double)fmaxf(rbs, 1.0f);                                     \
    int tmax = min((int)__popcll(__ballot(x >= THR)), BU);                   \
    float zmax = readlane_f(PM, tmax);                                       \
    unsigned long long ball = __ballot((ZF == zmax) && (t <= tmax));         \
    int act = __builtin_amdgcn_readfirstlane(__ffsll(ball) - 1);             \
    float essum = readlane_f(PS, tmax);                                      \
    ACT = act;                                                               \
    LP  = readlane_f(SCF, act) - __logf(essum);                              \
    unsigned long long mb = __ballot((t <= tmax) && (BASE == 0.0f));         \
    LM = (__popcll(mb) > 1) ? 1.0f : 0.0f;                                   \
    prev = act;                                                              \
  }
  P_STAGE(r.p1a, r.lp2, r.lm2, ipw2, thr3, bu1, pm3, ps3, z3f, sc3f, base1)
  P_STAGE(r.p2a, r.lp3, r.lm3, ipw3, thr5, bu2, pm4, ps4, z4f, sc4f, base2)
  P_STAGE(r.p3a, r.lp4, r.lm4, ipw5, thr7, bu3, pm5, ps5, z5f, sc5f, base3)
#undef P_STAGE

  return r;
}

// ---------------------------------------------------------------------------
// Main kernel: 2 rows per wave (independent streams interleave to hide the
// serial sample-chain and load latency). 4 waves / 256-thread block.
// ---------------------------------------------------------------------------
__global__ __launch_bounds__(256) void pt_kernel(
    const int*   __restrict__ loop_ind_p,          // [1]
    const float* __restrict__ order_mask,          // [B,O]
    const int*   __restrict__ tile_remain_budgets, // [B,L,P]
    const float* __restrict__ tile_masks,          // [B,L,P,T]
    const float* __restrict__ remain_buffer_size,  // [B]
    const int*   __restrict__ tile2_max,           // [B]
    const float* __restrict__ max_temporal_tile2,  // [B]
    const int*   __restrict__ sp_tile2_max,        // [B]
    const int*   __restrict__ sp_tile2_min,        // [B]
    const float* __restrict__ order_logit,         // [B,O]
    const float* __restrict__ tile_logits,         // [B,P,T]
    const float* __restrict__ sp_tile2_logit,      // [B,T]
    float*       __restrict__ out,                 // [21*B]
    int B, int O, int T, int P, int L, Keys keys) {
  const int wave = threadIdx.x >> 6;
  const int t    = threadIdx.x & 63;
  const int w    = blockIdx.x * (blockDim.x >> 6) + wave;
  const int b0   = w * 2;
  if (b0 >= B) return;
  const int b1 = b0 + 1;

  const int bs0 = __builtin_amdgcn_readfirstlane(b0);
  const int bs1 = __builtin_amdgcn_readfirstlane(min(b1, B - 1));
  const int li  = loop_ind_p[0];

  // per-lane constant tables (shared by both rows)
  double thr3 = THR3.v[t], thr5 = THR5.v[t], thr7 = THR7.v[t];
  double ipw2 = IPW2.v[t], ipw3 = IPW3.v[t], ipw5 = IPW5.v[t];

  RowRes ra = process_row(bs0, t, li, O, T, P, L, keys,
                          thr3, thr5, thr7, ipw2, ipw3, ipw5,
                          order_mask, tile_remain_budgets, tile_masks,
                          remain_buffer_size, tile2_max, max_temporal_tile2,
                          sp_tile2_max, sp_tile2_min, order_logit,
                          tile_logits, sp_tile2_logit);
  RowRes rb = process_row(bs1, t, li, O, T, P, L, keys,
                          thr3, thr5, thr7, ipw2, ipw3, ipw5,
                          order_mask, tile_remain_budgets, tile_masks,
                          remain_buffer_size, tile2_max, max_temporal_tile2,
                          sp_tile2_max, sp_tile2_min, order_logit,
                          tile_logits, sp_tile2_logit);

  // ---- epilogue: all RowRes fields are wave-uniform; lane 0 writes row A,
  // lane 1 writes row B (concurrent store issue).
  if (t < 2) {
    int bb = (t == 0) ? b0 : b1;
    if (bb < B) {
      RowRes r = (t == 0) ? ra : rb;
      size_t Bz = (size_t)B;
      out[bb] = (float)r.oa;
      float4 ta4; ta4.x = (float)r.t2a; ta4.y = (float)r.p1a;
      ta4.z = (float)r.p2a; ta4.w = (float)r.p3a;
      *(float4*)(out + Bz + (size_t)bb * 4) = ta4;
      float4 sa4; sa4.x = (float)r.spa; sa4.y = 0.0f;
      sa4.z = 0.0f; sa4.w = 0.0f;
      *(float4*)(out + Bz * 5 + (size_t)bb * 4) = sa4;
      float* lp = out + Bz * 9 + (size_t)bb * 6;
      float2 a, c, d;
      a.x = r.lp0; a.y = r.lp1;  *(float2*)(lp) = a;
      c.x = r.lp2; c.y = r.lp3;  *(float2*)(lp + 2) = c;
      d.x = r.lp4; d.y = r.lp5;  *(float2*)(lp + 4) = d;
      float* lm = out + Bz * 15 + (size_t)bb * 6;
      a.x = r.lm0; a.y = r.lm1;  *(float2*)(lm) = a;
      c.x = r.lm2; c.y = r.lm3;  *(float2*)(lm + 2) = c;
      d.x = r.lm4; d.y = r.lm5;  *(float2*)(lm + 4) = d;
    }
  }
}

// ---------------------------------------------------------------------------
extern "C" void kernel_launch(void* const* d_in, const int* in_sizes, int n_in,
                              void* d_out, int out_size, void* d_ws,
                              size_t ws_size, hipStream_t stream) {
  const int B = in_sizes[6];                 // remain_buffer_size: [B]
  const int O = in_sizes[1] / B;             // order_mask: [B,O]
  const int T = in_sizes[13] / B;            // sp_tile2_logit: [B,T]
  const int P = in_sizes[12] / (B * T);      // tile_logits: [B,P,T]
  const int L = in_sizes[2] / (B * P);       // tile_remain_budgets: [B,L,P]

  // keys = jax.random.split(jax.random.key(1), 6), threefry-partitionable
  Keys keys;
  for (int j = 0; j < 6; ++j) {
    uint32_t x0 = 0u, x1 = (uint32_t)j;
    tf2x32(0u, 1u, x0, x1);
    keys.k[2 * j]     = x0;
    keys.k[2 * j + 1] = x1;
  }

  const int wavesPerBlock = 4;
  const int rowsPerBlock  = wavesPerBlock * 2;
  dim3 block(wavesPerBlock * 64);
  dim3 grid((B + rowsPerBlock - 1) / rowsPerBlock);
  pt_kernel<<<grid, block, 0, stream>>>(
      (const int*)d_in[5],            // loop_ind
      (const float*)d_in[1],          // order_mask
      (const int*)d_in[2],            // tile_remain_budgets
      (const float*)d_in[3],          // tile_masks
      (const float*)d_in[6],          // remain_buffer_size
      (const int*)d_in[7],            // tile2_max
      (const float*)d_in[8],          // max_temporal_tile2
      (const int*)d_in[9],            // sp_tile2_max
      (const int*)d_in[10],           // sp_tile2_min
      (const float*)d_in[11],         // order_logit
      (const float*)d_in[12],         // tile_logits
      (const float*)d_in[13],         // sp_tile2_logit
      (float*)d_out, B, O, T, P, L, keys);
}